// Round 4
// 604.407 us; speedup vs baseline: 1.0064x; 1.0064x over previous
//
#include <hip/hip_runtime.h>

// Problem constants (from reference)
constexpr int T_FRAMES = 96;
constexpr int HH = 720;
constexpr int WW = 1280;
constexpr int HW = HH * WW;            // 921600
constexpr int N_NOISE = 10;

constexpr int PIX = 4;                 // pixels per thread (float4)
constexpr int BLOCK = 64;              // 1 wave per block -> fine-grained balance
constexpr int NBLOCKS = HW / PIX / BLOCK;  // 3600 blocks, ~14.06 per CU

typedef float f4 __attribute__((ext_vector_type(4)));

// ---------------------------------------------------------------------------
// Noise dtype resolution — settled by round-3 evidence:
//   * in_sizes[] are ELEMENT counts (traceback: to_numpy(np.float32,(out_size,)))
//     so buffer-size-based host dispatch is impossible.
//   * The u8 path failed absmax with noise-placement errors (255 vs 0/127),
//     proving the staged noise arrays are WIDENED 4-byte elements.
//   * A nonzero-BIT test on int4 is simultaneously correct for int32 0/1 and
//     float32 0.0/1.0f (bool-derived data never contains -0.0, the only
//     nonzero-bit value that compares == 0.0f).
// => One hardcoded 4-byte bit-test path; no runtime detect, no memset, no
//    serialization chain. Inputs are staged once per identifier, so the
//    dtype cannot change between runs.
// ---------------------------------------------------------------------------

// Load 4 noise elements (4-byte each) at element index idx (multiple of 4)
// and pack to a 4-bit mask via nonzero-bit test.
__device__ __forceinline__ unsigned pack4(const void* __restrict__ p, int idx) {
    const int4 v = *(reinterpret_cast<const int4*>(
        reinterpret_cast<const int*>(p) + idx));
    return (v.x ? 1u : 0u) | (v.y ? 2u : 0u) | (v.z ? 4u : 0u) | (v.w ? 8u : 0u);
}

__device__ __forceinline__ float classify(float cur, float prev,
                                          unsigned on, unsigned off) {
    const float d = cur - prev;
    float o = (d == 0.f) ? 127.f : (d > 0.f ? 255.f : 0.f);
    if (on)  o = 255.f;   // on-noise forces 255 ...
    if (off) o = 0.f;     // ... but off-noise wins (matches reference nesting)
    return o;
}

__global__ __launch_bounds__(BLOCK)
void neuro_kernel(const float* __restrict__ tensor,
                  const float* __restrict__ state,
                  const void* __restrict__ on_noise,
                  const void* __restrict__ off_noise,
                  float* __restrict__ out) {
    const int p = (blockIdx.x * BLOCK + threadIdx.x) * PIX;

    // Prefetch + bit-pack ALL noise for this thread's 4 pixels:
    // bit (ni*4 + k) = noise[ni][p + k]. 40 bits per array.
    unsigned long long onb = 0, offb = 0;
#pragma unroll
    for (int ni = 0; ni < N_NOISE; ++ni) {
        onb  |= (unsigned long long)pack4(on_noise,  ni * HW + p) << (ni * 4);
        offb |= (unsigned long long)pack4(off_noise, ni * HW + p) << (ni * 4);
    }

    f4 prev = *reinterpret_cast<const f4*>(state + p);   // zeros in practice
    const float* tp = tensor + p;
    float*       op = out + p;

    int ni = 1;                                          // cnt % N_NOISE at t=0
#pragma unroll 8
    for (int t = 0; t < T_FRAMES; ++t) {
        const f4 cur = __builtin_nontemporal_load(reinterpret_cast<const f4*>(tp));
        const unsigned mon  = (unsigned)(onb  >> (ni * 4)) & 0xFu;
        const unsigned moff = (unsigned)(offb >> (ni * 4)) & 0xFu;

        f4 o;
        o.x = classify(cur.x, prev.x, mon & 1u, moff & 1u);
        o.y = classify(cur.y, prev.y, mon & 2u, moff & 2u);
        o.z = classify(cur.z, prev.z, mon & 4u, moff & 4u);
        o.w = classify(cur.w, prev.w, mon & 8u, moff & 8u);

        __builtin_nontemporal_store(o, reinterpret_cast<f4*>(op));
        prev = cur;
        tp += HW;
        op += HW;
        ni = (ni == N_NOISE - 1) ? 0 : ni + 1;           // uniform (scalar) update
    }
}

extern "C" void kernel_launch(void* const* d_in, const int* in_sizes, int n_in,
                              void* d_out, int out_size, void* d_ws, size_t ws_size,
                              hipStream_t stream) {
    const float* tensor   = (const float*)d_in[0];   // (T,H,W) f32
    const float* state    = (const float*)d_in[1];   // (H,W) f32
    // d_in[2] = timesurface (H,W) f32 — provably unused (refractory is a no-op)
    const void*  on_noise  = d_in[3];                // (N_NOISE,H,W) widened 4-byte bool
    const void*  off_noise = d_in[4];
    float* out = (float*)d_out;                      // (T,H,W) f32

    neuro_kernel<<<NBLOCKS, BLOCK, 0, stream>>>(
        tensor, state, on_noise, off_noise, out);
}

// Round 5
// 602.144 us; speedup vs baseline: 1.0101x; 1.0038x over previous
//
#include <hip/hip_runtime.h>

// Problem constants (from reference)
constexpr int T_FRAMES = 96;
constexpr int HH = 720;
constexpr int WW = 1280;
constexpr int HW = HH * WW;            // 921600
constexpr int N_NOISE = 10;

constexpr int BLOCK  = 64;             // 1 wave per block
constexpr int CHUNK  = BLOCK * 4;      // 256 floats = 1 KB per wave-chunk (f4/lane)
constexpr int NCH    = 2;              // chunks per wave -> 2 KB contiguous per frame
constexpr int PIXBLK = CHUNK * NCH;    // 512 floats per block per frame
constexpr int NBLOCKS = HW / PIXBLK;   // 1800 blocks, ~7.03 per CU

typedef float f4 __attribute__((ext_vector_type(4)));

// ---------------------------------------------------------------------------
// Round-4 result: 604.4 us passing. Window = 2 harness fills (~220 us each,
// 6.4 TB/s pure-write) + neuro (~164 us => 4.79 TB/s effective on 785 MB).
// Copy ceiling (also mixed r+w) is 6.29 TB/s -> the gap is NOT r/w turnaround.
// Theory: 1 KB-granular scattered access (wave chunk, then 3.69 MB frame jump)
// thrashes DRAM rows. Fix: each wave owns TWO chunk-strided f4s
// (p1 = p0 + 256 floats) -> every VMEM inst stays perfectly coalesced at 1 KB
// while the wave covers 2 KB contiguous per frame, doubling row burst length.
//
// Noise dtype (settled round 3): arrays are staged widened 4-byte; a
// nonzero-BIT test on int4 is correct for both int32 0/1 and float32 0/1.0f
// (bool-derived data never contains -0.0).
// ---------------------------------------------------------------------------

// Load 4 noise elements (4-byte each) at element index idx (multiple of 4)
// and pack to a 4-bit mask via nonzero-bit test.
__device__ __forceinline__ unsigned pack4(const void* __restrict__ p, int idx) {
    const int4 v = *(reinterpret_cast<const int4*>(
        reinterpret_cast<const int*>(p) + idx));
    return (v.x ? 1u : 0u) | (v.y ? 2u : 0u) | (v.z ? 4u : 0u) | (v.w ? 8u : 0u);
}

__device__ __forceinline__ float classify(float cur, float prev,
                                          unsigned on, unsigned off) {
    const float d = cur - prev;
    float o = (d == 0.f) ? 127.f : (d > 0.f ? 255.f : 0.f);
    if (on)  o = 255.f;   // on-noise forces 255 ...
    if (off) o = 0.f;     // ... but off-noise wins (matches reference nesting)
    return o;
}

__device__ __forceinline__ f4 classify4(f4 cur, f4 prev,
                                        unsigned mon, unsigned moff) {
    f4 o;
    o.x = classify(cur.x, prev.x, mon & 1u, moff & 1u);
    o.y = classify(cur.y, prev.y, mon & 2u, moff & 2u);
    o.z = classify(cur.z, prev.z, mon & 4u, moff & 4u);
    o.w = classify(cur.w, prev.w, mon & 8u, moff & 8u);
    return o;
}

__global__ __launch_bounds__(BLOCK)
void neuro_kernel(const float* __restrict__ tensor,
                  const float* __restrict__ state,
                  const void* __restrict__ on_noise,
                  const void* __restrict__ off_noise,
                  float* __restrict__ out) {
    const int p0 = blockIdx.x * PIXBLK + threadIdx.x * 4;  // chunk 0 (1 KB/wave)
    const int p1 = p0 + CHUNK;                             // chunk 1 (next 1 KB)

    // Prefetch + bit-pack ALL noise for both chunks:
    // bit (ni*4 + k) of {on,off}b{0,1} = noise[ni][p{0,1} + k]. 40 bits each.
    unsigned long long onb0 = 0, offb0 = 0, onb1 = 0, offb1 = 0;
#pragma unroll
    for (int ni = 0; ni < N_NOISE; ++ni) {
        onb0  |= (unsigned long long)pack4(on_noise,  ni * HW + p0) << (ni * 4);
        onb1  |= (unsigned long long)pack4(on_noise,  ni * HW + p1) << (ni * 4);
        offb0 |= (unsigned long long)pack4(off_noise, ni * HW + p0) << (ni * 4);
        offb1 |= (unsigned long long)pack4(off_noise, ni * HW + p1) << (ni * 4);
    }

    f4 prev0 = *reinterpret_cast<const f4*>(state + p0);   // zeros in practice
    f4 prev1 = *reinterpret_cast<const f4*>(state + p1);
    const float* tp = tensor + p0;
    float*       op = out + p0;

    int ni = 1;                                            // cnt % N_NOISE at t=0
#pragma unroll 4
    for (int t = 0; t < T_FRAMES; ++t) {
        const f4 cur0 = __builtin_nontemporal_load(reinterpret_cast<const f4*>(tp));
        const f4 cur1 = __builtin_nontemporal_load(reinterpret_cast<const f4*>(tp + CHUNK));
        const unsigned mon0  = (unsigned)(onb0  >> (ni * 4)) & 0xFu;
        const unsigned moff0 = (unsigned)(offb0 >> (ni * 4)) & 0xFu;
        const unsigned mon1  = (unsigned)(onb1  >> (ni * 4)) & 0xFu;
        const unsigned moff1 = (unsigned)(offb1 >> (ni * 4)) & 0xFu;

        const f4 o0 = classify4(cur0, prev0, mon0, moff0);
        const f4 o1 = classify4(cur1, prev1, mon1, moff1);

        __builtin_nontemporal_store(o0, reinterpret_cast<f4*>(op));
        __builtin_nontemporal_store(o1, reinterpret_cast<f4*>(op + CHUNK));
        prev0 = cur0;
        prev1 = cur1;
        tp += HW;
        op += HW;
        ni = (ni == N_NOISE - 1) ? 0 : ni + 1;             // uniform (scalar) update
    }
}

extern "C" void kernel_launch(void* const* d_in, const int* in_sizes, int n_in,
                              void* d_out, int out_size, void* d_ws, size_t ws_size,
                              hipStream_t stream) {
    const float* tensor   = (const float*)d_in[0];   // (T,H,W) f32
    const float* state    = (const float*)d_in[1];   // (H,W) f32
    // d_in[2] = timesurface (H,W) f32 — provably unused (refractory is a no-op)
    const void*  on_noise  = d_in[3];                // (N_NOISE,H,W) widened 4-byte bool
    const void*  off_noise = d_in[4];
    float* out = (float*)d_out;                      // (T,H,W) f32

    neuro_kernel<<<NBLOCKS, BLOCK, 0, stream>>>(
        tensor, state, on_noise, off_noise, out);
}